// Round 2
// baseline (2165.617 us; speedup 1.0000x reference)
//
#include <hip/hip_runtime.h>
#include <hip/hip_bf16.h>
#include <stdint.h>

typedef __attribute__((ext_vector_type(8))) __bf16 bf16x8;
typedef __attribute__((ext_vector_type(4))) float  floatx4;

#define T_STEPS 256
#define BATCH   128
#define HID     512

__device__ __forceinline__ float sigmoidf_(float x) { return 1.f / (1.f + __expf(-x)); }
__device__ __forceinline__ float tanhf_(float y) {
  float e = __expf(-2.f * fabsf(y));
  return copysignf((1.f - e) / (1.f + e), y);
}

// Poll a single cumulative counter line until it reaches target.
// All 64 lanes load the SAME address -> one coalesced L3 request per sweep
// (vs 64 distinct lines/wave in the old per-producer-flag scheme: ~2000x
// less poll traffic chip-wide). Value is monotone non-decreasing.
template <int SLP>
__device__ __forceinline__ void pollctr_(const int* p, int target) {
  while (1) {
    int v = __hip_atomic_load(p, __ATOMIC_RELAXED, __HIP_MEMORY_SCOPE_AGENT);
    if (v >= target) break;
    __builtin_amdgcn_s_sleep(SLP);
  }
  asm volatile("" ::: "memory");
}

// Fused 2-layer persistent GRU scan, software-pipelined across layers.
// Grid = 256 blocks: [layer(2)][bg(2)][g(64)].
//   layer L, bg, g: owns hidden cols [8g,8g+8) for batch rows [64bg,64bg+64).
// h exchange: FRESH time-major slab per step (slab t = h after step t),
// plain cached b128 consumer loads (first toucher/XCD misses to L3, rest hit
// L2 -> the 64-way multicast is amortized). Correct because a consumer's
// FIRST touch of a slab line happens only after the flag, which is posted
// only after the producer's stores are ack'd at the coherence point.
// Flags (NEW this round): one cumulative counter per (layer, bg, row-group w)
// on its own 128B line. Producer wave w: packed 4B relaxed AGENT stores ->
// s_waitcnt vmcnt(0) -> lane0 atomic_fetch_add(+1) (fire-and-forget). No
// __syncthreads, no per-block flag. Consumer wave w (needs exactly rows
// [16w,16w+16) of its bg, i.e. wave-w output of all 64 g-blocks) polls its
// single line for ctr >= 64*(step+1). Monotone cumulative -> no reset/ABA;
// gating is acyclic (L0 ring self-contained, L1 gates on L0) -> no deadlock;
// all 256 blocks co-resident (64KiB LDS -> 2 blocks/CU cap, 256 <= 256 CUs).
// Cross-layer: layer-1 phaseX(t) reads h0 slab t gated on L0 ctr >= 64*(t+1).
// Layer-0 phaseX reads x directly as fp32 [b][t][256] (cvt folded in), done
// in the gap between flag post and own-ring poll to hide x refill.
__global__ __launch_bounds__(256) void gru_fused(
    const float* __restrict__ x,                              // [128][256][256] fp32
    const float* __restrict__ Wih0, const float* __restrict__ Whh0,
    const float* __restrict__ bih0, const float* __restrict__ bhh0,
    const float* __restrict__ Wih1, const float* __restrict__ Whh1,
    const float* __restrict__ bih1, const float* __restrict__ bhh1,
    __bf16* __restrict__ h0base,                              // [256][128][512]
    __bf16* __restrict__ h1base,                              // [256][128][512]
    int* __restrict__ fl)                                     // [2][2][4][32] ints
{
  const int tid   = threadIdx.x;
  const int layer = blockIdx.x >> 7;
  const int bg    = (blockIdx.x >> 6) & 1;
  const int g     = blockIdx.x & 63;
  const int w = tid >> 6, l = tid & 63, c = l & 15, q = l >> 4;
  const int Kin = layer ? HID : 256;
  const int KTx = Kin >> 5;            // 8 or 16
  const int KT  = KTx + 16;
  const int rowbase = bg * 64 + w * 16;
  const int jj  = g * 8 + c;

  const float* Wih = layer ? Wih1 : Wih0;
  const float* Whh = layer ? Whh1 : Whh0;
  const float* bih = layer ? bih1 : bih0;
  const float* bhh = layer ? bhh1 : bhh0;
  __bf16* hbase = layer ? h1base : h0base;

  __shared__ __bf16 ldsW[2 * 32 * 64 * 8];   // 64 KiB max (KT<=32)

  // ---- stage W slice (fp32 -> bf16) into frag-order LDS
  // tile0 cols: [r0..7 | z0..7], tile1 cols: [n0..7 | zeros]
  for (int cid = tid; cid < 2 * KT * 64; cid += 256) {
    int nt = cid / (KT * 64);
    int r1 = cid - nt * (KT * 64);
    int kt = r1 >> 6;
    int ll = r1 & 63;
    int cc = ll & 15, qq = ll >> 4;
    int k  = kt * 32 + qq * 8;
    int grow;
    if (nt == 0) grow = (cc < 8) ? (g * 8 + cc) : (512 + g * 8 + (cc - 8));
    else         grow = (cc < 8) ? (1024 + g * 8 + cc) : -1;
    bf16x8 v;
    if (grow >= 0) {
      const float* src = (k < Kin) ? (Wih + (size_t)grow * Kin + k)
                                   : (Whh + (size_t)grow * HID + (k - Kin));
      #pragma unroll
      for (int j = 0; j < 8; ++j) v[j] = (__bf16)src[j];
    } else {
      #pragma unroll
      for (int j = 0; j < 8; ++j) v[j] = (__bf16)0.f;
    }
    *(bf16x8*)&ldsW[((size_t)(nt * KT + kt) * 64 + ll) * 8] = v;
  }
  __syncthreads();   // only barrier; LDS is read-only afterwards

  // ---- hoist the h-part W fragments
  bf16x8 WH[16][2];
  #pragma unroll
  for (int kt = 0; kt < 16; ++kt) {
    WH[kt][0] = *(const bf16x8*)&ldsW[((size_t)(0 * KT + KTx + kt) * 64 + l) * 8];
    WH[kt][1] = *(const bf16x8*)&ldsW[((size_t)(1 * KT + KTx + kt) * 64 + l) * 8];
  }

  // ---- per-lane biases
  float bias0, bias_nx, bias_nh;
  if (c < 8) {
    bias0   = bih[jj] + bhh[jj];
    bias_nx = bih[1024 + jj];
    bias_nh = bhh[1024 + jj];
  } else {
    int j2 = g * 8 + (c - 8);
    bias0   = bih[512 + j2] + bhh[512 + j2];
    bias_nx = 0.f; bias_nh = 0.f;
  }

  floatx4 accA[2], accB[2];
  const floatx4 zero4 = {0.f, 0.f, 0.f, 0.f};
  float hprev[4] = {0.f, 0.f, 0.f, 0.f};

  // counter lines: [layer][bg][w] -- wave w posts & polls exactly its own
  // row-group line (it produces rows [16w,+16) and consumes the same rows).
  int*       fpost = fl + ((size_t)((layer * 2 + bg) * 4 + w)) * 32;
  const int* fown  = fpost;
  const int* fx    = fl + ((size_t)((0     * 2 + bg) * 4 + w)) * 32;  // L0 ring

  auto hslab = [&](int t) -> __bf16* {
    return hbase + (size_t)t * (BATCH * HID);
  };

  auto phaseX = [&](int t) {
    accA[0] = zero4; accA[1] = zero4;
    if (layer == 0) {
      const float* xp = x + ((size_t)(rowbase + c) * T_STEPS + t) * 256 + q * 8;
      for (int kt = 0; kt < 8; ++kt) {
        bf16x8 b0 = *(const bf16x8*)&ldsW[((size_t)(0 * KT + kt) * 64 + l) * 8];
        bf16x8 b1 = *(const bf16x8*)&ldsW[((size_t)(1 * KT + kt) * 64 + l) * 8];
        floatx4 u = *(const floatx4*)(xp + kt * 32);
        floatx4 v = *(const floatx4*)(xp + kt * 32 + 4);
        bf16x8 a;
        a[0] = (__bf16)u[0]; a[1] = (__bf16)u[1]; a[2] = (__bf16)u[2]; a[3] = (__bf16)u[3];
        a[4] = (__bf16)v[0]; a[5] = (__bf16)v[1]; a[6] = (__bf16)v[2]; a[7] = (__bf16)v[3];
        accA[0] = __builtin_amdgcn_mfma_f32_16x16x32_bf16(a, b0, accA[0], 0, 0, 0);
        accA[1] = __builtin_amdgcn_mfma_f32_16x16x32_bf16(a, b1, accA[1], 0, 0, 0);
      }
    } else {
      // x = h0 slab t (gated by caller on fx); plain cached loads
      const __bf16* xp = h0base + (size_t)t * (BATCH * HID)
                       + (size_t)(rowbase + c) * HID + q * 8;
      for (int kt = 0; kt < 16; ++kt) {
        bf16x8 b0 = *(const bf16x8*)&ldsW[((size_t)(0 * KT + kt) * 64 + l) * 8];
        bf16x8 b1 = *(const bf16x8*)&ldsW[((size_t)(1 * KT + kt) * 64 + l) * 8];
        bf16x8 a = *(const bf16x8*)(xp + kt * 32);
        accA[0] = __builtin_amdgcn_mfma_f32_16x16x32_bf16(a, b0, accA[0], 0, 0, 0);
        accA[1] = __builtin_amdgcn_mfma_f32_16x16x32_bf16(a, b1, accA[1], 0, 0, 0);
      }
    }
  };

  // ---- prologue
  if (layer == 1) pollctr_<2>(fx, 64);       // h0 slab 0 complete?
  phaseX(0);

  for (int t = 0; t < T_STEPS; ++t) {
    // ---- phase H: accB = h_{t-1} @ Whh_slice^T (plain cached b128 loads)
    accB[0] = zero4; accB[1] = zero4;
    if (t > 0) {
      const __bf16* hA = hslab(t - 1) + (size_t)(rowbase + c) * HID + q * 8;
      bf16x8 hfrag[16];
      #pragma unroll
      for (int kt = 0; kt < 16; ++kt)
        hfrag[kt] = *(const bf16x8*)(hA + kt * 32);
      #pragma unroll
      for (int kt = 0; kt < 16; ++kt) {
        accB[0] = __builtin_amdgcn_mfma_f32_16x16x32_bf16(hfrag[kt], WH[kt][0], accB[0], 0, 0, 0);
        accB[1] = __builtin_amdgcn_mfma_f32_16x16x32_bf16(hfrag[kt], WH[kt][1], accB[1], 0, 0, 0);
      }
    }

    // ---- epilogue: gates + h update; packed-pair agent stores (write-through)
    __bf16* hs = hslab(t);
    #pragma unroll
    for (int rg = 0; rg < 4; ++rg) {
      float pre0 = accA[0][rg] + accB[0][rg] + bias0;
      float zs = __shfl(pre0, (l & 48) | ((c + 8) & 15), 64);
      float r  = sigmoidf_(pre0);
      float z  = sigmoidf_(zs);
      float nn = tanhf_(accA[1][rg] + bias_nx + r * (accB[1][rg] + bias_nh));
      float hnew = (1.f - z) * nn + z * hprev[rg];
      hprev[rg] = hnew;
      unsigned short us = __builtin_bit_cast(unsigned short, (__bf16)hnew);
      int po = __shfl_xor((int)us, 1, 64);
      if (c < 8 && (c & 1) == 0) {
        uint32_t v = (uint32_t)us | ((uint32_t)po << 16);
        int row = rowbase + q * 4 + rg;
        __hip_atomic_store((uint32_t*)(hs + (size_t)row * HID + jj), v,
                           __ATOMIC_RELAXED, __HIP_MEMORY_SCOPE_AGENT);
      }
    }

    // drain THIS wave's h stores to the coherence point, then post +1 on the
    // row-group counter (no block barrier -- waves publish independently).
    asm volatile("s_waitcnt vmcnt(0)" ::: "memory");
    if (l == 0)
      (void)__hip_atomic_fetch_add(fpost, 1, __ATOMIC_RELAXED,
                                   __HIP_MEMORY_SCOPE_AGENT);

    if (t + 1 < T_STEPS) {
      if (layer == 1) pollctr_<2>(fx, 64 * (t + 2));  // h0 slab t+1 ready?
      phaseX(t + 1);                                  // hides flag flight / x refill
      pollctr_<1>(fown, 64 * (t + 1));                // peers' h_t visible?
    }
  }
}

// yhat[b][o] = h1_last[b][:] . Wout[o][:] + bout[o]
__global__ __launch_bounds__(64) void outproj(const __bf16* __restrict__ h1,
                                              const float* __restrict__ Wout,
                                              const float* __restrict__ bout,
                                              float* __restrict__ out) {
  int b = blockIdx.x, o = threadIdx.x;
  const __bf16* hr = h1 + (size_t)b * HID;
  const float*  wr = Wout + (size_t)o * HID;
  float acc = bout[o];
  for (int k = 0; k < HID; k += 8) {
    bf16x8 h8 = *(const bf16x8*)(hr + k);
    #pragma unroll
    for (int j = 0; j < 8; ++j) acc += (float)h8[j] * wr[k + j];
  }
  out[b * 64 + o] = acc;
}

extern "C" void kernel_launch(void* const* d_in, const int* in_sizes, int n_in,
                              void* d_out, int out_size, void* d_ws, size_t ws_size,
                              hipStream_t stream) {
  const float* x    = (const float*)d_in[0];
  const float* Wih0 = (const float*)d_in[1];
  const float* Whh0 = (const float*)d_in[2];
  const float* bih0 = (const float*)d_in[3];
  const float* bhh0 = (const float*)d_in[4];
  const float* Wih1 = (const float*)d_in[5];
  const float* Whh1 = (const float*)d_in[6];
  const float* bih1 = (const float*)d_in[7];
  const float* bhh1 = (const float*)d_in[8];
  const float* Wout = (const float*)d_in[9];
  const float* bout = (const float*)d_in[10];

  char* ws = (char*)d_ws;
  // ws layout (bytes):
  //   [0, 32 MiB)        h0seq: 256 slabs x 128 KB ([t][b][512] bf16)
  //   [32 MiB, 64 MiB)   h1seq: 256 slabs x 128 KB
  //   [64 MiB, +4 KiB)   counters [2 layer][2 bg][4 w] x 32 ints (128B lines)
  __bf16* h0 = (__bf16*)(ws);
  __bf16* h1 = (__bf16*)(ws + (32u << 20));
  int*    fl = (int*)(ws + (64u << 20));

  // zero the counter lines (ws is poisoned before every launch); h slabs need
  // no init -- consumers first-touch a slab line only after its flag.
  (void)hipMemsetAsync(fl, 0, 2 * 2 * 4 * 32 * 4, stream);

  // fused 2-layer pipelined scan: blocks [0,128) = layer 0, [128,256) = layer 1
  gru_fused<<<256, 256, 0, stream>>>(x,
                                     Wih0, Whh0, bih0, bhh0,
                                     Wih1, Whh1, bih1, bhh1,
                                     h0, h1, fl);

  // final h1 = slab 255
  outproj<<<128, 64, 0, stream>>>(h1 + (size_t)255 * BATCH * HID,
                                  Wout, bout, (float*)d_out);
}

// Round 3
// 1892.619 us; speedup vs baseline: 1.1442x; 1.1442x over previous
//
#include <hip/hip_runtime.h>
#include <hip/hip_bf16.h>
#include <stdint.h>

typedef __attribute__((ext_vector_type(8))) __bf16 bf16x8;
typedef __attribute__((ext_vector_type(4))) float  floatx4;

#define T_STEPS 256
#define BATCH   128
#define HID     512

__device__ __forceinline__ float sigmoidf_(float x) { return 1.f / (1.f + __expf(-x)); }
__device__ __forceinline__ float tanhf_(float y) {
  float e = __expf(-2.f * fabsf(y));
  return copysignf((1.f - e) / (1.f + e), y);
}

// poll a ring of 32 per-block flag lines until all watched values >= target.
// lane l watches line (l&31); 128B lines; relaxed agent loads.
template <int SLP>
__device__ __forceinline__ void pollring_(const int* base, int target) {
  const int* p = base + (size_t)(threadIdx.x & 31) * 32;
  while (1) {
    int v = __hip_atomic_load(p, __ATOMIC_RELAXED, __HIP_MEMORY_SCOPE_AGENT);
    if (__all(v >= target)) break;
    __builtin_amdgcn_s_sleep(SLP);
  }
  asm volatile("" ::: "memory");
}

// Fused 2-layer persistent GRU scan, software-pipelined across layers.
// ROUND-3 GEOMETRY: 256 blocks x 128 threads (2 waves): [layer(2)][bg(4)][g(32)].
//   Block (L,bg,g): owns hidden cols [16g,16g+16) for batch rows [32bg,32bg+32).
//   W slice = 48 preact rows x (Kin+512) in LDS (98 KB for layer 1) -> exactly
//   1 block/CU, all 256 co-resident. vs round-0: per-CU per-step reads drop
//   256KB -> 64KB (the on-chain L1-fill/L2 term), per-wave MFMA doubles
//   (48 -> 96), ring shrinks 64 -> 32 blocks (half the flag gather width,
//   posts, and pollers). 3 clean 16-col tiles (r,z,n): no zero padding, no
//   z-shuffle in the epilogue.
// h exchange (protocol = round-0's proven shape, best of 3 measured variants):
//   FRESH time-major slab per step. Producer: packed 4B relaxed AGENT stores
//   -> s_waitcnt vmcnt(0) -> __syncthreads -> tid0 stores t+1 to the block's
//   private 128B flag line. Consumer: pollring_ (lane l watches line l&31),
//   then plain cached b128 loads (fresh addresses => no staleness; first
//   toucher/XCD misses to L3, rest hit L2).
// Cross-layer: layer-1 phaseX(t) reads h0 slab t, gated on layer-0 ring flags
//   >= t+1; layer 0 runs ~1 step ahead in steady state.
// Dataflow is acyclic (L0 ring self-contained, L1 gates on L0); all blocks
// co-resident; polls sleep-paced -> no deadlock.
__global__ __launch_bounds__(128, 1) void gru_fused(
    const float* __restrict__ x,                              // [128][256][256] fp32
    const float* __restrict__ Wih0, const float* __restrict__ Whh0,
    const float* __restrict__ bih0, const float* __restrict__ bhh0,
    const float* __restrict__ Wih1, const float* __restrict__ Whh1,
    const float* __restrict__ bih1, const float* __restrict__ bhh1,
    __bf16* __restrict__ h0base,                              // [256][128][512]
    __bf16* __restrict__ h1base,                              // [256][128][512]
    int* __restrict__ fl)                                     // [2][4][32] lines x 32 ints
{
  const int tid   = threadIdx.x;
  const int layer = blockIdx.x >> 7;
  const int bg    = (blockIdx.x >> 5) & 3;
  const int g     = blockIdx.x & 31;
  const int w = tid >> 6, l = tid & 63, c = l & 15, q = l >> 4;
  const int Kin = layer ? HID : 256;
  const int KTx = Kin >> 5;            // 8 or 16
  const int KT  = KTx + 16;            // 24 or 32
  const int rowbase = bg * 32 + w * 16;
  const int jj  = g * 16 + c;

  const float* Wih = layer ? Wih1 : Wih0;
  const float* Whh = layer ? Whh1 : Whh0;
  const float* bih = layer ? bih1 : bih0;
  const float* bhh = layer ? bhh1 : bhh0;
  __bf16* hbase = layer ? h1base : h0base;

  __shared__ __bf16 ldsW[3 * 32 * 64 * 8];   // 98304 B (KT<=32) -> 1 block/CU

  // ---- stage W slice (fp32 -> bf16) into frag-order LDS
  // tile nt in {0,1,2} = {r,z,n}: preact rows [nt*512 + 16g, +16), K-major
  // fragments: elem(lane ll, j) = W[nt*512+16g+(ll&15)][kt*32+(ll>>4)*8+j]
  for (int cid = tid; cid < 3 * KT * 64; cid += 128) {
    int nt = cid / (KT * 64);
    int r1 = cid - nt * (KT * 64);
    int kt = r1 >> 6;
    int ll = r1 & 63;
    int cc = ll & 15, qq = ll >> 4;
    int k  = kt * 32 + qq * 8;
    int grow = nt * 512 + g * 16 + cc;
    const float* src = (k < Kin) ? (Wih + (size_t)grow * Kin + k)
                                 : (Whh + (size_t)grow * HID + (k - Kin));
    bf16x8 v;
    #pragma unroll
    for (int j = 0; j < 8; ++j) v[j] = (__bf16)src[j];
    *(bf16x8*)&ldsW[((size_t)(nt * KT + kt) * 64 + ll) * 8] = v;
  }
  __syncthreads();   // only barrier outside the step loop; LDS read-only after

  // ---- hoist the h-part W fragments (3 tiles x 16 k-tiles)
  bf16x8 WH[16][3];
  #pragma unroll
  for (int kt = 0; kt < 16; ++kt) {
    WH[kt][0] = *(const bf16x8*)&ldsW[((size_t)(0 * KT + KTx + kt) * 64 + l) * 8];
    WH[kt][1] = *(const bf16x8*)&ldsW[((size_t)(1 * KT + KTx + kt) * 64 + l) * 8];
    WH[kt][2] = *(const bf16x8*)&ldsW[((size_t)(2 * KT + KTx + kt) * 64 + l) * 8];
  }

  // ---- per-lane biases (every lane owns one hidden col jj)
  const float bias_r  = bih[jj]        + bhh[jj];
  const float bias_z  = bih[512 + jj]  + bhh[512 + jj];
  const float bias_nx = bih[1024 + jj];
  const float bias_nh = bhh[1024 + jj];

  floatx4 accA[3], accB[3];
  const floatx4 zero4 = {0.f, 0.f, 0.f, 0.f};
  float hprev[4] = {0.f, 0.f, 0.f, 0.f};

  int*       fpost = fl + ((size_t)((layer * 4 + bg) * 32 + g)) * 32;  // private line
  const int* fown  = fl + ((size_t)((layer * 4 + bg) * 32)) * 32;      // own ring
  const int* fx    = fl + ((size_t)((0     * 4 + bg) * 32)) * 32;      // layer-0 ring

  auto hslab = [&](int t) -> __bf16* {
    return hbase + (size_t)t * (BATCH * HID);
  };

  auto phaseX = [&](int t) {
    accA[0] = zero4; accA[1] = zero4; accA[2] = zero4;
    if (layer == 0) {
      const float* xp = x + ((size_t)(rowbase + c) * T_STEPS + t) * 256 + q * 8;
      for (int kt = 0; kt < 8; ++kt) {
        bf16x8 b0 = *(const bf16x8*)&ldsW[((size_t)(0 * KT + kt) * 64 + l) * 8];
        bf16x8 b1 = *(const bf16x8*)&ldsW[((size_t)(1 * KT + kt) * 64 + l) * 8];
        bf16x8 b2 = *(const bf16x8*)&ldsW[((size_t)(2 * KT + kt) * 64 + l) * 8];
        floatx4 u = *(const floatx4*)(xp + kt * 32);
        floatx4 v = *(const floatx4*)(xp + kt * 32 + 4);
        bf16x8 a;
        a[0] = (__bf16)u[0]; a[1] = (__bf16)u[1]; a[2] = (__bf16)u[2]; a[3] = (__bf16)u[3];
        a[4] = (__bf16)v[0]; a[5] = (__bf16)v[1]; a[6] = (__bf16)v[2]; a[7] = (__bf16)v[3];
        accA[0] = __builtin_amdgcn_mfma_f32_16x16x32_bf16(a, b0, accA[0], 0, 0, 0);
        accA[1] = __builtin_amdgcn_mfma_f32_16x16x32_bf16(a, b1, accA[1], 0, 0, 0);
        accA[2] = __builtin_amdgcn_mfma_f32_16x16x32_bf16(a, b2, accA[2], 0, 0, 0);
      }
    } else {
      // x = h0 slab t (caller gated on fx); plain cached loads
      const __bf16* xp = h0base + (size_t)t * (BATCH * HID)
                       + (size_t)(rowbase + c) * HID + q * 8;
      for (int kt = 0; kt < 16; ++kt) {
        bf16x8 b0 = *(const bf16x8*)&ldsW[((size_t)(0 * KT + kt) * 64 + l) * 8];
        bf16x8 b1 = *(const bf16x8*)&ldsW[((size_t)(1 * KT + kt) * 64 + l) * 8];
        bf16x8 b2 = *(const bf16x8*)&ldsW[((size_t)(2 * KT + kt) * 64 + l) * 8];
        bf16x8 a = *(const bf16x8*)(xp + kt * 32);
        accA[0] = __builtin_amdgcn_mfma_f32_16x16x32_bf16(a, b0, accA[0], 0, 0, 0);
        accA[1] = __builtin_amdgcn_mfma_f32_16x16x32_bf16(a, b1, accA[1], 0, 0, 0);
        accA[2] = __builtin_amdgcn_mfma_f32_16x16x32_bf16(a, b2, accA[2], 0, 0, 0);
      }
    }
  };

  // ---- prologue
  if (layer == 1) pollring_<2>(fx, 1);
  phaseX(0);

  for (int t = 0; t < T_STEPS; ++t) {
    // ---- phase H: accB = h_{t-1} @ Whh_slice^T (plain cached b128 loads)
    accB[0] = zero4; accB[1] = zero4; accB[2] = zero4;
    if (t > 0) {
      const __bf16* hA = hslab(t - 1) + (size_t)(rowbase + c) * HID + q * 8;
      bf16x8 hfrag[16];
      #pragma unroll
      for (int kt = 0; kt < 16; ++kt)
        hfrag[kt] = *(const bf16x8*)(hA + kt * 32);
      #pragma unroll
      for (int kt = 0; kt < 16; ++kt) {
        accB[0] = __builtin_amdgcn_mfma_f32_16x16x32_bf16(hfrag[kt], WH[kt][0], accB[0], 0, 0, 0);
        accB[1] = __builtin_amdgcn_mfma_f32_16x16x32_bf16(hfrag[kt], WH[kt][1], accB[1], 0, 0, 0);
        accB[2] = __builtin_amdgcn_mfma_f32_16x16x32_bf16(hfrag[kt], WH[kt][2], accB[2], 0, 0, 0);
      }
    }

    // ---- epilogue: gates + h update; packed-pair agent stores (write-through)
    // every lane owns col jj: no cross-lane shuffle needed for z anymore.
    __bf16* hs = hslab(t);
    #pragma unroll
    for (int rg = 0; rg < 4; ++rg) {
      float r  = sigmoidf_(accA[0][rg] + accB[0][rg] + bias_r);
      float z  = sigmoidf_(accA[1][rg] + accB[1][rg] + bias_z);
      float nn = tanhf_(accA[2][rg] + bias_nx + r * (accB[2][rg] + bias_nh));
      float hnew = (1.f - z) * nn + z * hprev[rg];
      hprev[rg] = hnew;
      unsigned short us = __builtin_bit_cast(unsigned short, (__bf16)hnew);
      int po = __shfl_xor((int)us, 1, 64);
      if ((c & 1) == 0) {
        uint32_t v = (uint32_t)us | ((uint32_t)po << 16);
        int row = rowbase + q * 4 + rg;
        __hip_atomic_store((uint32_t*)(hs + (size_t)row * HID + jj), v,
                           __ATOMIC_RELAXED, __HIP_MEMORY_SCOPE_AGENT);
      }
    }

    // drain h stores to the coherence point, then publish step t completion
    asm volatile("s_waitcnt vmcnt(0)" ::: "memory");
    __syncthreads();
    if (tid == 0)
      __hip_atomic_store(fpost, t + 1, __ATOMIC_RELAXED, __HIP_MEMORY_SCOPE_AGENT);

    if (t + 1 < T_STEPS) {
      if (layer == 1) pollring_<2>(fx, t + 2);  // h0 slab t+1 ready?
      phaseX(t + 1);                            // hides flag flight / x refill
      pollring_<1>(fown, t + 1);                // peers' h_t visible?
    }
  }
}

// yhat[b][o] = h1_last[b][:] . Wout[o][:] + bout[o]
__global__ __launch_bounds__(64) void outproj(const __bf16* __restrict__ h1,
                                              const float* __restrict__ Wout,
                                              const float* __restrict__ bout,
                                              float* __restrict__ out) {
  int b = blockIdx.x, o = threadIdx.x;
  const __bf16* hr = h1 + (size_t)b * HID;
  const float*  wr = Wout + (size_t)o * HID;
  float acc = bout[o];
  for (int k = 0; k < HID; k += 8) {
    bf16x8 h8 = *(const bf16x8*)(hr + k);
    #pragma unroll
    for (int j = 0; j < 8; ++j) acc += (float)h8[j] * wr[k + j];
  }
  out[b * 64 + o] = acc;
}

extern "C" void kernel_launch(void* const* d_in, const int* in_sizes, int n_in,
                              void* d_out, int out_size, void* d_ws, size_t ws_size,
                              hipStream_t stream) {
  const float* x    = (const float*)d_in[0];
  const float* Wih0 = (const float*)d_in[1];
  const float* Whh0 = (const float*)d_in[2];
  const float* bih0 = (const float*)d_in[3];
  const float* bhh0 = (const float*)d_in[4];
  const float* Wih1 = (const float*)d_in[5];
  const float* Whh1 = (const float*)d_in[6];
  const float* bih1 = (const float*)d_in[7];
  const float* bhh1 = (const float*)d_in[8];
  const float* Wout = (const float*)d_in[9];
  const float* bout = (const float*)d_in[10];

  char* ws = (char*)d_ws;
  // ws layout (bytes):
  //   [0, 32 MiB)        h0seq: 256 slabs x 128 KB ([t][b][512] bf16)
  //   [32 MiB, 64 MiB)   h1seq: 256 slabs x 128 KB
  //   [64 MiB, +32 KiB)  flags [2 layer][4 bg][32 g] x 32 ints (128B lines)
  __bf16* h0 = (__bf16*)(ws);
  __bf16* h1 = (__bf16*)(ws + (32u << 20));
  int*    fl = (int*)(ws + (64u << 20));

  // zero the flag lines (ws is poisoned before every launch); h slabs need no
  // init -- consumers first-touch a slab line only after its flag.
  (void)hipMemsetAsync(fl, 0, 2 * 4 * 32 * 32 * 4, stream);

  // fused 2-layer pipelined scan: blocks [0,128) = layer 0, [128,256) = layer 1
  gru_fused<<<256, 128, 0, stream>>>(x,
                                     Wih0, Whh0, bih0, bhh0,
                                     Wih1, Whh1, bih1, bhh1,
                                     h0, h1, fl);

  // final h1 = slab 255
  outproj<<<128, 64, 0, stream>>>(h1 + (size_t)255 * BATCH * HID,
                                  Wout, bout, (float*)d_out);
}